// Round 2
// baseline (1233.969 us; speedup 1.0000x reference)
//
#include <hip/hip_runtime.h>
#include <cstdint>

#define N_NODES 50000
#define N_EDGES 1600000
#define NH 4
#define CC 32
#define HC 128          // NH*CC
#define LAT 32
#define NEG_SLOPE 0.2f

// ---------------------------------------------------------------- kernels

// v[d*4+h] = sum_c W_edge[d,h*32+c] * att_edge[h,c]
__global__ void k_v(const float* __restrict__ W_edge,
                    const float* __restrict__ att_edge,
                    float* __restrict__ v) {
    int t = threadIdx.x;
    if (t < 28) {
        int d = t >> 2, h = t & 3;
        float s = 0.f;
        #pragma unroll
        for (int c = 0; c < 32; ++c)
            s += W_edge[d * 128 + h * 32 + c] * att_edge[h * 32 + c];
        v[t] = s;
    }
}

// xp[n, c] = sum_{i<3} x[n,i] * W_gat[i,c]
__global__ __launch_bounds__(256) void k_xp(const float* __restrict__ x,
                                            const float* __restrict__ W_gat,
                                            float* __restrict__ xp) {
    int k = blockIdx.x * 256 + threadIdx.x;
    if (k >= N_NODES * HC) return;
    int n = k >> 7, c = k & 127;
    float x0 = x[n * 3 + 0], x1 = x[n * 3 + 1], x2 = x[n * 3 + 2];
    xp[k] = x0 * W_gat[c] + x1 * W_gat[128 + c] + x2 * W_gat[256 + c];
}

// per edge: count in-degree + sum edge_attr per dst
// NOTE: harness delivers integer inputs as int32 (NOT the reference's int64)
__global__ __launch_bounds__(256) void k_deg(const int* __restrict__ ei,
                                             const float* __restrict__ edge_attr,
                                             int* __restrict__ cnt,
                                             float* __restrict__ ea_sum) {
    int e = blockIdx.x * 256 + threadIdx.x;
    if (e >= N_EDGES) return;
    int dst = ei[N_EDGES + e];
    atomicAdd(&cnt[dst], 1);
    #pragma unroll
    for (int d = 0; d < 7; ++d)
        atomicAdd(&ea_sum[dst * 7 + d], edge_attr[e * 7 + d]);
}

// single-block exclusive prefix sum over cnt -> rowptr[N+1]
__global__ __launch_bounds__(1024) void k_scan(const int* __restrict__ cnt,
                                               int* __restrict__ rowptr) {
    __shared__ int part[1024];
    int t = threadIdx.x;
    const int W = (N_NODES + 1023) / 1024;
    int lo = t * W, hi = min(lo + W, N_NODES);
    int s = 0;
    for (int i = lo; i < hi; ++i) s += cnt[i];
    part[t] = s;
    __syncthreads();
    for (int off = 1; off < 1024; off <<= 1) {
        int vv = (t >= off) ? part[t - off] : 0;
        __syncthreads();
        part[t] += vv;
        __syncthreads();
    }
    int run = part[t] - s;   // exclusive base
    for (int i = lo; i < hi; ++i) { rowptr[i] = run; run += cnt[i]; }
    if (t == 1023) rowptr[N_NODES] = part[1023];
}

// per (n,h): a_src, a_dst, self-loop softmax weight exp(leakyrelu(...))
__global__ __launch_bounds__(256) void k_node(const float* __restrict__ xp,
                                              const float* __restrict__ att_src,
                                              const float* __restrict__ att_dst,
                                              const int* __restrict__ cnt,
                                              const float* __restrict__ ea_sum,
                                              const float* __restrict__ v,
                                              float* __restrict__ a_src,
                                              float* __restrict__ a_dst,
                                              float* __restrict__ es_self) {
    int id = blockIdx.x * 256 + threadIdx.x;
    if (id >= N_NODES * NH) return;
    int n = id >> 2, h = id & 3;
    const float* xr = xp + n * 128 + h * 32;
    float as = 0.f, ad = 0.f;
    #pragma unroll
    for (int c = 0; c < 32; ++c) {
        float xv = xr[c];
        as += xv * att_src[h * 32 + c];
        ad += xv * att_dst[h * 32 + c];
    }
    a_src[id] = as;
    a_dst[id] = ad;
    float invd = 1.0f / fmaxf((float)cnt[n], 1.0f);
    float ae = 0.f;
    #pragma unroll
    for (int d = 0; d < 7; ++d)
        ae += (ea_sum[n * 7 + d] * invd) * v[d * 4 + h];
    float al = as + ad + ae;
    al = al > 0.f ? al : NEG_SLOPE * al;
    es_self[id] = __expf(al);
}

// per edge: w[h] = exp(leakyrelu(a_src[src]+a_dst[dst]+a_edge)); scatter to CSR slot
__global__ __launch_bounds__(256) void k_edge(const int* __restrict__ ei,
                                              const float* __restrict__ edge_attr,
                                              const float* __restrict__ a_src,
                                              const float* __restrict__ a_dst,
                                              const float* __restrict__ v,
                                              const int* __restrict__ rowptr,
                                              int* __restrict__ cnt2,
                                              float4* __restrict__ w_csr,
                                              int* __restrict__ src_csr) {
    __shared__ float vs[28];
    if (threadIdx.x < 28) vs[threadIdx.x] = v[threadIdx.x];
    __syncthreads();
    int e = blockIdx.x * 256 + threadIdx.x;
    if (e >= N_EDGES) return;
    int src = ei[e];
    int dst = ei[N_EDGES + e];
    float ea[7];
    #pragma unroll
    for (int d = 0; d < 7; ++d) ea[d] = edge_attr[e * 7 + d];
    float4 as4 = ((const float4*)a_src)[src];
    float4 ad4 = ((const float4*)a_dst)[dst];
    float asv[4] = {as4.x, as4.y, as4.z, as4.w};
    float adv[4] = {ad4.x, ad4.y, ad4.z, ad4.w};
    float w[4];
    #pragma unroll
    for (int h = 0; h < 4; ++h) {
        float aeh = 0.f;
        #pragma unroll
        for (int d = 0; d < 7; ++d) aeh += ea[d] * vs[d * 4 + h];
        float al = asv[h] + adv[h] + aeh;
        al = al > 0.f ? al : NEG_SLOPE * al;
        w[h] = __expf(al);
    }
    int pos = rowptr[dst] + atomicAdd(&cnt2[dst], 1);
    w_csr[pos] = make_float4(w[0], w[1], w[2], w[3]);
    src_csr[pos] = src;
}

// one block per node: gather incoming messages, softmax-normalize, +bias, ELU
__global__ __launch_bounds__(128) void k_gather(const int* __restrict__ rowptr,
                                                const float* __restrict__ w_csr,
                                                const int* __restrict__ src_csr,
                                                const float* __restrict__ xp,
                                                const float* __restrict__ es_self,
                                                const float* __restrict__ bias_gat,
                                                float* __restrict__ h_buf) {
    int n = blockIdx.x;
    int c = threadIdx.x;          // channel 0..127
    int h = c >> 5;               // head
    int start = rowptr[n], end = rowptr[n + 1];
    float acc = 0.f, den = 0.f;
    for (int p = start; p < end; ++p) {
        int s = src_csr[p];
        float w = w_csr[p * 4 + h];
        acc += w * xp[s * 128 + c];
        den += w;
    }
    float w0 = es_self[n * 4 + h];
    acc += w0 * xp[n * 128 + c];
    den += w0;
    float o = acc / den + bias_gat[c];
    o = o > 0.f ? o : (__expf(o) - 1.0f);   // ELU(alpha=1)
    h_buf[n * 128 + c] = o;
}

// h1 = PReLU(h @ W1 + b1); 2 rows per 256-thread block
__global__ __launch_bounds__(256) void k_mlp1(const float* __restrict__ h_buf,
                                              const float* __restrict__ W1,
                                              const float* __restrict__ b1,
                                              const float* __restrict__ prelu_a,
                                              float* __restrict__ h1) {
    __shared__ float sh[2][128];
    int r = threadIdx.x >> 7;
    int k = threadIdx.x & 127;
    int n = blockIdx.x * 2 + r;
    sh[r][k] = h_buf[n * 128 + k];
    __syncthreads();
    float acc = b1[k];
    #pragma unroll 8
    for (int d = 0; d < 128; ++d)
        acc += sh[r][d] * W1[d * 128 + k];
    float a = prelu_a[0];
    acc = acc > 0.f ? acc : a * acc;
    h1[n * 128 + k] = acc;
}

// out = h1 @ W2 + b2; 8 rows per 256-thread block
__global__ __launch_bounds__(256) void k_mlp2(const float* __restrict__ h1,
                                              const float* __restrict__ W2,
                                              const float* __restrict__ b2,
                                              float* __restrict__ out) {
    __shared__ float sh[8][128];
    int tid = threadIdx.x;
    int nb = blockIdx.x * 8;
    #pragma unroll
    for (int i = 0; i < 4; ++i) {
        int idx = tid + i * 256;
        int rr = idx >> 7, dd = idx & 127;
        sh[rr][dd] = h1[(nb + rr) * 128 + dd];
    }
    __syncthreads();
    int r = tid >> 5, j = tid & 31;
    float acc = b2[j];
    #pragma unroll 8
    for (int d = 0; d < 128; ++d)
        acc += sh[r][d] * W2[d * 32 + j];
    out[(nb + r) * 32 + j] = acc;
}

// ---------------------------------------------------------------- launch

extern "C" void kernel_launch(void* const* d_in, const int* in_sizes, int n_in,
                              void* d_out, int out_size, void* d_ws, size_t ws_size,
                              hipStream_t stream) {
    const float* x        = (const float*)d_in[0];
    const int*   ei       = (const int*)d_in[1];     // int32 per harness contract
    const float* edge_attr= (const float*)d_in[2];
    const float* W_gat    = (const float*)d_in[3];
    const float* att_src  = (const float*)d_in[4];
    const float* att_dst  = (const float*)d_in[5];
    const float* W_edge   = (const float*)d_in[6];
    const float* att_edge = (const float*)d_in[7];
    const float* bias_gat = (const float*)d_in[8];
    const float* W1       = (const float*)d_in[9];
    const float* b1       = (const float*)d_in[10];
    const float* prelu_a  = (const float*)d_in[11];
    const float* W2       = (const float*)d_in[12];
    const float* b2       = (const float*)d_in[13];
    float*       out      = (float*)d_out;

    // workspace carve-up (256B aligned)
    char* base = (char*)d_ws;
    size_t off = 0;
    auto alloc = [&](size_t bytes) -> void* {
        void* p = base + off;
        off = (off + bytes + 255) & ~(size_t)255;
        return p;
    };
    int*   cnt     = (int*)  alloc((size_t)N_NODES * 4);
    int*   cnt2    = (int*)  alloc((size_t)N_NODES * 4);
    float* ea_sum  = (float*)alloc((size_t)N_NODES * 7 * 4);
    int*   rowptr  = (int*)  alloc((size_t)(N_NODES + 1) * 4);
    float* v       = (float*)alloc(32 * 4);
    float* a_src   = (float*)alloc((size_t)N_NODES * 4 * 4);
    float* a_dst   = (float*)alloc((size_t)N_NODES * 4 * 4);
    float* es_self = (float*)alloc((size_t)N_NODES * 4 * 4);
    float* xp      = (float*)alloc((size_t)N_NODES * 128 * 4);
    float* w_csr   = (float*)alloc((size_t)N_EDGES * 4 * 4);
    int*   src_csr = (int*)  alloc((size_t)N_EDGES * 4);
    float* h_buf   = (float*)alloc((size_t)N_NODES * 128 * 4);
    float* h1      = xp;   // xp dead after k_gather; reuse for h1

    hipMemsetAsync(cnt,    0, (size_t)N_NODES * 4, stream);
    hipMemsetAsync(cnt2,   0, (size_t)N_NODES * 4, stream);
    hipMemsetAsync(ea_sum, 0, (size_t)N_NODES * 7 * 4, stream);

    k_v   <<<1, 32, 0, stream>>>(W_edge, att_edge, v);
    k_xp  <<<(N_NODES * HC + 255) / 256, 256, 0, stream>>>(x, W_gat, xp);
    k_deg <<<(N_EDGES + 255) / 256, 256, 0, stream>>>(ei, edge_attr, cnt, ea_sum);
    k_scan<<<1, 1024, 0, stream>>>(cnt, rowptr);
    k_node<<<(N_NODES * NH + 255) / 256, 256, 0, stream>>>(
        xp, att_src, att_dst, cnt, ea_sum, v, a_src, a_dst, es_self);
    k_edge<<<(N_EDGES + 255) / 256, 256, 0, stream>>>(
        ei, edge_attr, a_src, a_dst, v, rowptr, cnt2, (float4*)w_csr, src_csr);
    k_gather<<<N_NODES, 128, 0, stream>>>(
        rowptr, w_csr, src_csr, xp, es_self, bias_gat, h_buf);
    k_mlp1<<<N_NODES / 2, 256, 0, stream>>>(h_buf, W1, b1, prelu_a, h1);
    k_mlp2<<<N_NODES / 8, 256, 0, stream>>>(h1, W2, b2, out);
}

// Round 3
// 726.562 us; speedup vs baseline: 1.6984x; 1.6984x over previous
//
#include <hip/hip_runtime.h>
#include <cstdint>

#define N_NODES 50000
#define N_EDGES 1600000
#define NH 4
#define CC 32
#define HC 128          // NH*CC
#define LAT 32
#define NEG_SLOPE 0.2f

// ---------------------------------------------------------------- kernels

// v[d*4+h] = sum_c W_edge[d,h*32+c] * att_edge[h,c]
__global__ void k_v(const float* __restrict__ W_edge,
                    const float* __restrict__ att_edge,
                    float* __restrict__ v) {
    int t = threadIdx.x;
    if (t < 28) {
        int d = t >> 2, h = t & 3;
        float s = 0.f;
        #pragma unroll
        for (int c = 0; c < 32; ++c)
            s += W_edge[d * 128 + h * 32 + c] * att_edge[h * 32 + c];
        v[t] = s;
    }
}

// xp[n, c] = sum_{i<3} x[n,i] * W_gat[i,c]
__global__ __launch_bounds__(256) void k_xp(const float* __restrict__ x,
                                            const float* __restrict__ W_gat,
                                            float* __restrict__ xp) {
    int k = blockIdx.x * 256 + threadIdx.x;
    if (k >= N_NODES * HC) return;
    int n = k >> 7, c = k & 127;
    float x0 = x[n * 3 + 0], x1 = x[n * 3 + 1], x2 = x[n * 3 + 2];
    xp[k] = x0 * W_gat[c] + x1 * W_gat[128 + c] + x2 * W_gat[256 + c];
}

// per edge: count in-degree ONLY (int atomics; the 7 fp32 atomics/edge of the
// old k_deg were 620us of serialized L2 atomics — eliminated via linearity of
// the ea_mean . v contraction, now aggregated through the CSR in k_gather)
__global__ __launch_bounds__(256) void k_cnt(const int* __restrict__ ei,
                                             int* __restrict__ cnt) {
    int e = blockIdx.x * 256 + threadIdx.x;
    if (e >= N_EDGES) return;
    atomicAdd(&cnt[ei[N_EDGES + e]], 1);
}

// single-block exclusive prefix sum over cnt -> rowptr[N+1]
__global__ __launch_bounds__(1024) void k_scan(const int* __restrict__ cnt,
                                               int* __restrict__ rowptr) {
    __shared__ int part[1024];
    int t = threadIdx.x;
    const int W = (N_NODES + 1023) / 1024;
    int lo = t * W, hi = min(lo + W, N_NODES);
    int s = 0;
    for (int i = lo; i < hi; ++i) s += cnt[i];
    part[t] = s;
    __syncthreads();
    for (int off = 1; off < 1024; off <<= 1) {
        int vv = (t >= off) ? part[t - off] : 0;
        __syncthreads();
        part[t] += vv;
        __syncthreads();
    }
    int run = part[t] - s;   // exclusive base
    for (int i = lo; i < hi; ++i) { rowptr[i] = run; run += cnt[i]; }
    if (t == 1023) rowptr[N_NODES] = part[1023];
}

// per (n,h): a_src, a_dst
__global__ __launch_bounds__(256) void k_node(const float* __restrict__ xp,
                                              const float* __restrict__ att_src,
                                              const float* __restrict__ att_dst,
                                              float* __restrict__ a_src,
                                              float* __restrict__ a_dst) {
    int id = blockIdx.x * 256 + threadIdx.x;
    if (id >= N_NODES * NH) return;
    int n = id >> 2, h = id & 3;
    const float* xr = xp + n * 128 + h * 32;
    float as = 0.f, ad = 0.f;
    #pragma unroll
    for (int c = 0; c < 32; ++c) {
        float xv = xr[c];
        as += xv * att_src[h * 32 + c];
        ad += xv * att_dst[h * 32 + c];
    }
    a_src[id] = as;
    a_dst[id] = ad;
}

// per edge: aeh[h] = edge_attr . v[:,h]; w[h] = exp(leakyrelu(as+ad+aeh));
// scatter {w4, aeh4, src} to CSR slot
__global__ __launch_bounds__(256) void k_edge(const int* __restrict__ ei,
                                              const float* __restrict__ edge_attr,
                                              const float* __restrict__ a_src,
                                              const float* __restrict__ a_dst,
                                              const float* __restrict__ v,
                                              const int* __restrict__ rowptr,
                                              int* __restrict__ cnt2,
                                              float4* __restrict__ w_csr,
                                              float4* __restrict__ ae_csr,
                                              int* __restrict__ src_csr) {
    __shared__ float vs[28];
    if (threadIdx.x < 28) vs[threadIdx.x] = v[threadIdx.x];
    __syncthreads();
    int e = blockIdx.x * 256 + threadIdx.x;
    if (e >= N_EDGES) return;
    int src = ei[e];
    int dst = ei[N_EDGES + e];
    float ea[7];
    #pragma unroll
    for (int d = 0; d < 7; ++d) ea[d] = edge_attr[e * 7 + d];
    float4 as4 = ((const float4*)a_src)[src];
    float4 ad4 = ((const float4*)a_dst)[dst];
    float asv[4] = {as4.x, as4.y, as4.z, as4.w};
    float adv[4] = {ad4.x, ad4.y, ad4.z, ad4.w};
    float w[4], aeo[4];
    #pragma unroll
    for (int h = 0; h < 4; ++h) {
        float aeh = 0.f;
        #pragma unroll
        for (int d = 0; d < 7; ++d) aeh += ea[d] * vs[d * 4 + h];
        aeo[h] = aeh;
        float al = asv[h] + adv[h] + aeh;
        al = al > 0.f ? al : NEG_SLOPE * al;
        w[h] = __expf(al);
    }
    int pos = rowptr[dst] + atomicAdd(&cnt2[dst], 1);
    w_csr[pos]  = make_float4(w[0], w[1], w[2], w[3]);
    ae_csr[pos] = make_float4(aeo[0], aeo[1], aeo[2], aeo[3]);
    src_csr[pos] = src;
}

// one block (128 thr) per node: self-loop weight from mean(aeh), gather
// incoming messages, softmax-normalize, +bias, ELU
__global__ __launch_bounds__(128) void k_gather(const int* __restrict__ rowptr,
                                                const float* __restrict__ w_csr,
                                                const float* __restrict__ ae_csr,
                                                const int* __restrict__ src_csr,
                                                const float* __restrict__ xp,
                                                const float* __restrict__ a_src,
                                                const float* __restrict__ a_dst,
                                                const float* __restrict__ bias_gat,
                                                float* __restrict__ h_buf) {
    int n = blockIdx.x;
    int c = threadIdx.x;          // channel 0..127
    int h = c >> 5;               // head
    int j = c & 31;               // lane within head
    int start = rowptr[n], end = rowptr[n + 1];
    int deg = end - start;

    // prologue: mean over incoming edges of aeh[.,h] -> self-loop weight
    float aesum = 0.f;
    for (int p = start + j; p < end; p += 32)
        aesum += ae_csr[p * 4 + h];
    #pragma unroll
    for (int k = 16; k >= 1; k >>= 1)
        aesum += __shfl_xor(aesum, k, 32);
    float invd = 1.0f / fmaxf((float)deg, 1.0f);
    float al = a_src[n * 4 + h] + a_dst[n * 4 + h] + aesum * invd;
    al = al > 0.f ? al : NEG_SLOPE * al;
    float w0 = __expf(al);

    float acc = 0.f, den = 0.f;
    for (int p = start; p < end; ++p) {
        int s = src_csr[p];
        float w = w_csr[p * 4 + h];
        acc += w * xp[s * 128 + c];
        den += w;
    }
    acc += w0 * xp[n * 128 + c];
    den += w0;
    float o = acc / den + bias_gat[c];
    o = o > 0.f ? o : (__expf(o) - 1.0f);   // ELU(alpha=1)
    h_buf[n * 128 + c] = o;
}

// h1 = PReLU(h @ W1 + b1); 2 rows per 256-thread block
__global__ __launch_bounds__(256) void k_mlp1(const float* __restrict__ h_buf,
                                              const float* __restrict__ W1,
                                              const float* __restrict__ b1,
                                              const float* __restrict__ prelu_a,
                                              float* __restrict__ h1) {
    __shared__ float sh[2][128];
    int r = threadIdx.x >> 7;
    int k = threadIdx.x & 127;
    int n = blockIdx.x * 2 + r;
    sh[r][k] = h_buf[n * 128 + k];
    __syncthreads();
    float acc = b1[k];
    #pragma unroll 8
    for (int d = 0; d < 128; ++d)
        acc += sh[r][d] * W1[d * 128 + k];
    float a = prelu_a[0];
    acc = acc > 0.f ? acc : a * acc;
    h1[n * 128 + k] = acc;
}

// out = h1 @ W2 + b2; 8 rows per 256-thread block
__global__ __launch_bounds__(256) void k_mlp2(const float* __restrict__ h1,
                                              const float* __restrict__ W2,
                                              const float* __restrict__ b2,
                                              float* __restrict__ out) {
    __shared__ float sh[8][128];
    int tid = threadIdx.x;
    int nb = blockIdx.x * 8;
    #pragma unroll
    for (int i = 0; i < 4; ++i) {
        int idx = tid + i * 256;
        int rr = idx >> 7, dd = idx & 127;
        sh[rr][dd] = h1[(nb + rr) * 128 + dd];
    }
    __syncthreads();
    int r = tid >> 5, j = tid & 31;
    float acc = b2[j];
    #pragma unroll 8
    for (int d = 0; d < 128; ++d)
        acc += sh[r][d] * W2[d * 32 + j];
    out[(nb + r) * 32 + j] = acc;
}

// ---------------------------------------------------------------- launch

extern "C" void kernel_launch(void* const* d_in, const int* in_sizes, int n_in,
                              void* d_out, int out_size, void* d_ws, size_t ws_size,
                              hipStream_t stream) {
    const float* x        = (const float*)d_in[0];
    const int*   ei       = (const int*)d_in[1];     // int32 per harness contract
    const float* edge_attr= (const float*)d_in[2];
    const float* W_gat    = (const float*)d_in[3];
    const float* att_src  = (const float*)d_in[4];
    const float* att_dst  = (const float*)d_in[5];
    const float* W_edge   = (const float*)d_in[6];
    const float* att_edge = (const float*)d_in[7];
    const float* bias_gat = (const float*)d_in[8];
    const float* W1       = (const float*)d_in[9];
    const float* b1       = (const float*)d_in[10];
    const float* prelu_a  = (const float*)d_in[11];
    const float* W2       = (const float*)d_in[12];
    const float* b2       = (const float*)d_in[13];
    float*       out      = (float*)d_out;

    // workspace carve-up (256B aligned)
    char* base = (char*)d_ws;
    size_t off = 0;
    auto alloc = [&](size_t bytes) -> void* {
        void* p = base + off;
        off = (off + bytes + 255) & ~(size_t)255;
        return p;
    };
    int*   cnt     = (int*)  alloc((size_t)N_NODES * 4);
    int*   cnt2    = (int*)  alloc((size_t)N_NODES * 4);
    int*   rowptr  = (int*)  alloc((size_t)(N_NODES + 1) * 4);
    float* v       = (float*)alloc(32 * 4);
    float* a_src   = (float*)alloc((size_t)N_NODES * 4 * 4);
    float* a_dst   = (float*)alloc((size_t)N_NODES * 4 * 4);
    float* xp      = (float*)alloc((size_t)N_NODES * 128 * 4);
    float* w_csr   = (float*)alloc((size_t)N_EDGES * 4 * 4);
    float* ae_csr  = (float*)alloc((size_t)N_EDGES * 4 * 4);
    int*   src_csr = (int*)  alloc((size_t)N_EDGES * 4);
    float* h_buf   = (float*)alloc((size_t)N_NODES * 128 * 4);
    float* h1      = xp;   // xp dead after k_gather; reuse for h1

    hipMemsetAsync(cnt,  0, (size_t)N_NODES * 4, stream);
    hipMemsetAsync(cnt2, 0, (size_t)N_NODES * 4, stream);

    k_v   <<<1, 32, 0, stream>>>(W_edge, att_edge, v);
    k_xp  <<<(N_NODES * HC + 255) / 256, 256, 0, stream>>>(x, W_gat, xp);
    k_cnt <<<(N_EDGES + 255) / 256, 256, 0, stream>>>(ei, cnt);
    k_scan<<<1, 1024, 0, stream>>>(cnt, rowptr);
    k_node<<<(N_NODES * NH + 255) / 256, 256, 0, stream>>>(
        xp, att_src, att_dst, a_src, a_dst);
    k_edge<<<(N_EDGES + 255) / 256, 256, 0, stream>>>(
        ei, edge_attr, a_src, a_dst, v, rowptr, cnt2,
        (float4*)w_csr, (float4*)ae_csr, src_csr);
    k_gather<<<N_NODES, 128, 0, stream>>>(
        rowptr, w_csr, ae_csr, src_csr, xp, a_src, a_dst, bias_gat, h_buf);
    k_mlp1<<<N_NODES / 2, 256, 0, stream>>>(h_buf, W1, b1, prelu_a, h1);
    k_mlp2<<<N_NODES / 8, 256, 0, stream>>>(h1, W2, b2, out);
}

// Round 4
// 538.988 us; speedup vs baseline: 2.2894x; 1.3480x over previous
//
#include <hip/hip_runtime.h>
#include <cstdint>

#define N_NODES 50000
#define N_EDGES 1600000
#define NH 4
#define CC 32
#define HC 128          // NH*CC
#define LAT 32
#define NEG_SLOPE 0.2f

// ---------------- bf16 helpers (RNE pack, shift-unpack) ----------------
__device__ __forceinline__ float bflo(uint32_t u) {
    union { uint32_t i; float f; } c; c.i = u << 16; return c.f;
}
__device__ __forceinline__ float bfhi(uint32_t u) {
    union { uint32_t i; float f; } c; c.i = u & 0xFFFF0000u; return c.f;
}
__device__ __forceinline__ uint32_t f2bf(float f) {
    union { float f; uint32_t i; } c; c.f = f;
    return (c.i + 0x7FFFu + ((c.i >> 16) & 1u)) >> 16;
}
__device__ __forceinline__ uint32_t pack2(float a, float b) {
    return f2bf(a) | (f2bf(b) << 16);
}

// ---------------------------------------------------------------- kernels

// small precompute:
//   v[d*4+h]     = sum_c W_edge[d,h*32+c] * att_edge[h,c]        (d<7)
//   u_src[i*4+h] = sum_c W_gat [i,h*32+c] * att_src[h,c]         (i<3)
//   u_dst[i*4+h] = sum_c W_gat [i,h*32+c] * att_dst[h,c]
__global__ void k_v(const float* __restrict__ W_edge,
                    const float* __restrict__ att_edge,
                    const float* __restrict__ W_gat,
                    const float* __restrict__ att_src,
                    const float* __restrict__ att_dst,
                    float* __restrict__ v,
                    float* __restrict__ u_src,
                    float* __restrict__ u_dst) {
    int t = threadIdx.x;
    if (t < 28) {
        int d = t >> 2, h = t & 3;
        float s = 0.f;
        #pragma unroll
        for (int c = 0; c < 32; ++c)
            s += W_edge[d * 128 + h * 32 + c] * att_edge[h * 32 + c];
        v[t] = s;
    } else if (t < 40) {
        int q = t - 28; int i = q >> 2, h = q & 3;
        float s = 0.f;
        #pragma unroll
        for (int c = 0; c < 32; ++c)
            s += W_gat[i * 128 + h * 32 + c] * att_src[h * 32 + c];
        u_src[q] = s;
    } else if (t < 52) {
        int q = t - 40; int i = q >> 2, h = q & 3;
        float s = 0.f;
        #pragma unroll
        for (int c = 0; c < 32; ++c)
            s += W_gat[i * 128 + h * 32 + c] * att_dst[h * 32 + c];
        u_dst[q] = s;
    }
}

// xp2[n*64+l] = bf16x2 of (xp[n,2l], xp[n,2l+1]); fp32 xp never materialized
__global__ __launch_bounds__(256) void k_xp(const float* __restrict__ x,
                                            const float* __restrict__ W_gat,
                                            uint32_t* __restrict__ xp2) {
    int k = blockIdx.x * 256 + threadIdx.x;
    if (k >= N_NODES * 64) return;
    int n = k >> 6, c = (k & 63) * 2;
    float x0 = x[n * 3 + 0], x1 = x[n * 3 + 1], x2 = x[n * 3 + 2];
    float a = x0 * W_gat[c]     + x1 * W_gat[128 + c]     + x2 * W_gat[256 + c];
    float b = x0 * W_gat[c + 1] + x1 * W_gat[128 + c + 1] + x2 * W_gat[256 + c + 1];
    xp2[k] = pack2(a, b);
}

// per edge: count in-degree (int atomics only)
__global__ __launch_bounds__(256) void k_cnt(const int* __restrict__ ei,
                                             int* __restrict__ cnt) {
    int e = blockIdx.x * 256 + threadIdx.x;
    if (e >= N_EDGES) return;
    atomicAdd(&cnt[ei[N_EDGES + e]], 1);
}

// single-block exclusive prefix sum over cnt -> rowptr[N+1]
__global__ __launch_bounds__(1024) void k_scan(const int* __restrict__ cnt,
                                               int* __restrict__ rowptr) {
    __shared__ int part[1024];
    int t = threadIdx.x;
    const int W = (N_NODES + 1023) / 1024;
    int lo = t * W, hi = min(lo + W, N_NODES);
    int s = 0;
    for (int i = lo; i < hi; ++i) s += cnt[i];
    part[t] = s;
    __syncthreads();
    for (int off = 1; off < 1024; off <<= 1) {
        int vv = (t >= off) ? part[t - off] : 0;
        __syncthreads();
        part[t] += vv;
        __syncthreads();
    }
    int run = part[t] - s;   // exclusive base
    for (int i = lo; i < hi; ++i) { rowptr[i] = run; run += cnt[i]; }
    if (t == 1023) rowptr[N_NODES] = part[1023];
}

// per node: a_src[n,h] = x[n,:].u_src[:,h]; a_dst likewise (3-dots, exact fp32)
__global__ __launch_bounds__(256) void k_node(const float* __restrict__ x,
                                              const float* __restrict__ u_src,
                                              const float* __restrict__ u_dst,
                                              float4* __restrict__ a_src,
                                              float4* __restrict__ a_dst) {
    int n = blockIdx.x * 256 + threadIdx.x;
    if (n >= N_NODES) return;
    float x0 = x[n * 3 + 0], x1 = x[n * 3 + 1], x2 = x[n * 3 + 2];
    float s[4], d[4];
    #pragma unroll
    for (int h = 0; h < 4; ++h) {
        s[h] = x0 * u_src[h] + x1 * u_src[4 + h] + x2 * u_src[8 + h];
        d[h] = x0 * u_dst[h] + x1 * u_dst[4 + h] + x2 * u_dst[8 + h];
    }
    a_src[n] = make_float4(s[0], s[1], s[2], s[3]);
    a_dst[n] = make_float4(d[0], d[1], d[2], d[3]);
}

// per edge: aeh = edge_attr.v; w = exp(leakyrelu(as+ad+aeh));
// scatter bf16-packed {w4, ae4} + src to CSR slot. edge_attr staged via LDS.
__global__ __launch_bounds__(256) void k_edge(const int* __restrict__ ei,
                                              const float* __restrict__ edge_attr,
                                              const float4* __restrict__ a_src,
                                              const float4* __restrict__ a_dst,
                                              const float* __restrict__ v,
                                              const int* __restrict__ rowptr,
                                              int* __restrict__ cnt2,
                                              uint2* __restrict__ w_csr,
                                              uint2* __restrict__ ae_csr,
                                              int* __restrict__ src_csr) {
    __shared__ float vs[28];
    __shared__ float ea_s[256 * 7];
    int t = threadIdx.x;
    if (t < 28) vs[t] = v[t];
    int e0 = blockIdx.x * 256;
    #pragma unroll
    for (int i = 0; i < 7; ++i)
        ea_s[t + i * 256] = edge_attr[e0 * 7 + t + i * 256];   // coalesced
    __syncthreads();
    int e = e0 + t;
    if (e >= N_EDGES) return;
    int src = ei[e];
    int dst = ei[N_EDGES + e];
    float ea[7];
    #pragma unroll
    for (int d = 0; d < 7; ++d) ea[d] = ea_s[t * 7 + d];
    float4 as4 = a_src[src];
    float4 ad4 = a_dst[dst];
    float asv[4] = {as4.x, as4.y, as4.z, as4.w};
    float adv[4] = {ad4.x, ad4.y, ad4.z, ad4.w};
    float w[4], aeo[4];
    #pragma unroll
    for (int h = 0; h < 4; ++h) {
        float aeh = 0.f;
        #pragma unroll
        for (int d = 0; d < 7; ++d) aeh += ea[d] * vs[d * 4 + h];
        aeo[h] = aeh;
        float al = asv[h] + adv[h] + aeh;
        al = al > 0.f ? al : NEG_SLOPE * al;
        w[h] = __expf(al);
    }
    int pos = rowptr[dst] + atomicAdd(&cnt2[dst], 1);
    w_csr[pos]  = make_uint2(pack2(w[0], w[1]),   pack2(w[2], w[3]));
    ae_csr[pos] = make_uint2(pack2(aeo[0], aeo[1]), pack2(aeo[2], aeo[3]));
    src_csr[pos] = src;
}

// one wave (64 thr) per node, 2 channels/lane: self-loop weight from mean(aeh),
// gather bf16 messages, softmax-normalize, +bias, ELU
__global__ __launch_bounds__(64) void k_gather(const int* __restrict__ rowptr,
                                               const uint16_t* __restrict__ w_csr_h,
                                               const uint16_t* __restrict__ ae_csr_h,
                                               const int* __restrict__ src_csr,
                                               const uint32_t* __restrict__ xp2,
                                               const float* __restrict__ a_src,
                                               const float* __restrict__ a_dst,
                                               const float* __restrict__ bias_gat,
                                               float2* __restrict__ h_buf) {
    int n = blockIdx.x;
    int l = threadIdx.x;          // lane 0..63; channels 2l, 2l+1
    int h = l >> 4;               // head
    int start = rowptr[n], end = rowptr[n + 1];
    int deg = end - start;

    // mean over incoming edges of aeh[.,h] -> self-loop attention logit
    float aesum = 0.f;
    for (int p = start + (l & 15); p < end; p += 16)
        aesum += bflo((uint32_t)ae_csr_h[p * 4 + h]);
    #pragma unroll
    for (int k = 8; k >= 1; k >>= 1)
        aesum += __shfl_xor(aesum, k);
    float invd = (deg > 0) ? (1.0f / (float)deg) : 1.0f;
    float al = a_src[n * 4 + h] + a_dst[n * 4 + h] + aesum * invd;
    al = al > 0.f ? al : NEG_SLOPE * al;
    float w0 = __expf(al);

    float acc0 = 0.f, acc1 = 0.f, den = 0.f;
    for (int p = start; p < end; ++p) {
        float w = bflo((uint32_t)w_csr_h[p * 4 + h]);
        uint32_t xu = xp2[src_csr[p] * 64 + l];
        acc0 += w * bflo(xu);
        acc1 += w * bfhi(xu);
        den  += w;
    }
    uint32_t xs = xp2[n * 64 + l];
    acc0 += w0 * bflo(xs);
    acc1 += w0 * bfhi(xs);
    den  += w0;

    float2 bia = ((const float2*)bias_gat)[l];
    float r = 1.0f / den;
    float o0 = acc0 * r + bia.x;
    float o1 = acc1 * r + bia.y;
    o0 = o0 > 0.f ? o0 : (__expf(o0) - 1.0f);   // ELU
    o1 = o1 > 0.f ? o1 : (__expf(o1) - 1.0f);
    h_buf[n * 64 + l] = make_float2(o0, o1);
}

// fused MLP: out = PReLU(h @ W1 + b1) @ W2 + b2 ; 8 rows per 256-thread block
__global__ __launch_bounds__(256) void k_mlp(const float* __restrict__ h_buf,
                                             const float* __restrict__ W1,
                                             const float* __restrict__ b1,
                                             const float* __restrict__ prelu_a,
                                             const float* __restrict__ W2,
                                             const float* __restrict__ b2,
                                             float* __restrict__ out) {
    __shared__ float sh[8][128];
    __shared__ float sh1[8][128];
    int t = threadIdx.x;
    int nb = blockIdx.x * 8;
    #pragma unroll
    for (int i = 0; i < 4; ++i) {
        int idx = t + i * 256;
        sh[idx >> 7][idx & 127] = h_buf[nb * 128 + idx];
    }
    __syncthreads();
    int k = t & 127, g = t >> 7;          // g in {0,1}: rows g*4..g*4+3
    float acc[4];
    float bb = b1[k];
    #pragma unroll
    for (int r = 0; r < 4; ++r) acc[r] = bb;
    for (int d = 0; d < 128; ++d) {
        float wv = W1[d * 128 + k];
        #pragma unroll
        for (int r = 0; r < 4; ++r)
            acc[r] += sh[g * 4 + r][d] * wv;
    }
    float a = prelu_a[0];
    #pragma unroll
    for (int r = 0; r < 4; ++r) {
        float vv = acc[r];
        sh1[g * 4 + r][k] = vv > 0.f ? vv : a * vv;
    }
    __syncthreads();
    int j = t & 31, r2 = t >> 5;
    float o = b2[j];
    for (int d = 0; d < 128; ++d)
        o += sh1[r2][d] * W2[d * 32 + j];
    out[(nb + r2) * 32 + j] = o;
}

// ---------------------------------------------------------------- launch

extern "C" void kernel_launch(void* const* d_in, const int* in_sizes, int n_in,
                              void* d_out, int out_size, void* d_ws, size_t ws_size,
                              hipStream_t stream) {
    const float* x        = (const float*)d_in[0];
    const int*   ei       = (const int*)d_in[1];     // int32 per harness contract
    const float* edge_attr= (const float*)d_in[2];
    const float* W_gat    = (const float*)d_in[3];
    const float* att_src  = (const float*)d_in[4];
    const float* att_dst  = (const float*)d_in[5];
    const float* W_edge   = (const float*)d_in[6];
    const float* att_edge = (const float*)d_in[7];
    const float* bias_gat = (const float*)d_in[8];
    const float* W1       = (const float*)d_in[9];
    const float* b1       = (const float*)d_in[10];
    const float* prelu_a  = (const float*)d_in[11];
    const float* W2       = (const float*)d_in[12];
    const float* b2       = (const float*)d_in[13];
    float*       out      = (float*)d_out;

    char* base = (char*)d_ws;
    size_t off = 0;
    auto alloc = [&](size_t bytes) -> void* {
        void* p = base + off;
        off = (off + bytes + 255) & ~(size_t)255;
        return p;
    };
    int*      cnt     = (int*)     alloc((size_t)N_NODES * 4);
    int*      cnt2    = (int*)     alloc((size_t)N_NODES * 4);
    int*      rowptr  = (int*)     alloc((size_t)(N_NODES + 1) * 4);
    float*    v       = (float*)   alloc(32 * 4);
    float*    u_src   = (float*)   alloc(16 * 4);
    float*    u_dst   = (float*)   alloc(16 * 4);
    float*    a_src   = (float*)   alloc((size_t)N_NODES * 4 * 4);
    float*    a_dst   = (float*)   alloc((size_t)N_NODES * 4 * 4);
    uint32_t* xp2     = (uint32_t*)alloc((size_t)N_NODES * 64 * 4);
    uint2*    w_csr   = (uint2*)   alloc((size_t)N_EDGES * 8);
    uint2*    ae_csr  = (uint2*)   alloc((size_t)N_EDGES * 8);
    int*      src_csr = (int*)     alloc((size_t)N_EDGES * 4);
    float*    h_buf   = (float*)   alloc((size_t)N_NODES * 128 * 4);

    hipMemsetAsync(cnt,  0, (size_t)N_NODES * 4, stream);
    hipMemsetAsync(cnt2, 0, (size_t)N_NODES * 4, stream);

    k_v   <<<1, 64, 0, stream>>>(W_edge, att_edge, W_gat, att_src, att_dst,
                                 v, u_src, u_dst);
    k_xp  <<<(N_NODES * 64 + 255) / 256, 256, 0, stream>>>(x, W_gat, xp2);
    k_cnt <<<(N_EDGES + 255) / 256, 256, 0, stream>>>(ei, cnt);
    k_scan<<<1, 1024, 0, stream>>>(cnt, rowptr);
    k_node<<<(N_NODES + 255) / 256, 256, 0, stream>>>(
        x, u_src, u_dst, (float4*)a_src, (float4*)a_dst);
    k_edge<<<N_EDGES / 256, 256, 0, stream>>>(
        ei, edge_attr, (const float4*)a_src, (const float4*)a_dst, v,
        rowptr, cnt2, w_csr, ae_csr, src_csr);
    k_gather<<<N_NODES, 64, 0, stream>>>(
        rowptr, (const uint16_t*)w_csr, (const uint16_t*)ae_csr, src_csr,
        xp2, a_src, a_dst, bias_gat, (float2*)h_buf);
    k_mlp <<<N_NODES / 8, 256, 0, stream>>>(h_buf, W1, b1, prelu_a, W2, b2, out);
}